// Round 18
// baseline (252.002 us; speedup 1.0000x reference)
//
#include <hip/hip_runtime.h>
#include <stdint.h>

#define NN 50000
#define NE 600000
#define ND 128
#define NH 512
#define NO 128
#define MPAD 50176  // 196 * 256
#define NB 196      // ceil(NN/256) scan blocks

typedef unsigned short u16;
typedef uint8_t u8;
typedef __attribute__((ext_vector_type(8))) short bf16x8;
typedef __attribute__((ext_vector_type(4))) float f32x4;
typedef __attribute__((ext_vector_type(2))) float f32x2;

__device__ __forceinline__ u16 f2bf(float f) {
  union { float f; uint32_t u; } v; v.f = f;
  uint32_t u = v.u;
  uint32_t r = (u + 0x7fffu + ((u >> 16) & 1u)) >> 16;
  return (u16)r;
}
__device__ __forceinline__ float bf2f(u16 h) {
  union { uint32_t u; float f; } v; v.u = ((uint32_t)h) << 16; return v.f;
}
__device__ __forceinline__ uint64_t f42bfq(float4 v) {
  union { u16 u[4]; uint64_t q; } o;
  o.u[0] = f2bf(v.x); o.u[1] = f2bf(v.y); o.u[2] = f2bf(v.z); o.u[3] = f2bf(v.w);
  return o.q;
}

// ---- fp8 e4m3 (OCP) encode/decode: HW cvt on gfx950, SW fallback ----
#if defined(__has_builtin)
#if __has_builtin(__builtin_amdgcn_cvt_pk_f32_fp8) && __has_builtin(__builtin_amdgcn_cvt_pk_fp8_f32)
#define HW_FP8 1
#endif
#endif
#ifndef HW_FP8
#define HW_FP8 0
#endif

__device__ __forceinline__ u8 f2fp8(float f) {
#if HW_FP8
  return (u8)(__builtin_amdgcn_cvt_pk_fp8_f32(f, f, 0, false) & 0xff);
#else
  union { float f; uint32_t u; } v; v.f = f;
  uint32_t s = v.u >> 31;
  float a = fabsf(f);
  if (a >= 448.f) return (u8)((s << 7) | 0x7e);
  if (a < 0.015625f) {
    uint32_t m = (uint32_t)(a * 512.0f + 0.5f);
    if (m > 7) return (u8)((s << 7) | 8);
    return (u8)((s << 7) | m);
  }
  uint32_t u = v.u & 0x7fffffff;
  uint32_t r = u + 0x7FFFF + ((u >> 20) & 1);
  int e8 = (int)(r >> 23) - 120;
  if (e8 >= 16) return (u8)((s << 7) | 0x7e);
  return (u8)((s << 7) | ((uint32_t)e8 << 3) | ((r >> 20) & 7));
#endif
}

template<bool HI>
__device__ __forceinline__ f32x2 fp8x2_f32(uint32_t w) {
#if HW_FP8
  return __builtin_amdgcn_cvt_pk_f32_fp8((int)w, HI);
#else
  uint32_t h = HI ? (w >> 16) : w;
  f32x2 r;
  for (int i = 0; i < 2; ++i) {
    uint32_t b = (h >> (i * 8)) & 0xff;
    uint32_t s = (b >> 7) & 1, e = (b >> 3) & 15, m = b & 7;
    float t;
    if (e == 0) t = (float)m * 0.001953125f;
    else { union { uint32_t u; float f; } v; v.u = ((e + 120) << 23) | (m << 20); t = v.f; }
    r[i] = s ? -t : t;
  }
  return r;
#endif
}

__device__ __forceinline__ void gld16(const u16* g, u16* l) {
  __builtin_amdgcn_global_load_lds(
      (const __attribute__((address_space(1))) void*)g,
      (__attribute__((address_space(3))) void*)l, 16, 0, 0);
}

// ---------------------------------------------------------------------------
// GEMM: C[M,512] = A[M,K](bf16) @ B^T   B stored transposed [512,K] bf16
// 256x256 tile, 512 threads (8 waves, 2m x 4n; wave = 128x64 output).
// T4 counted-vmcnt pipeline (r13): A,B double-buffered LDS (128 KB);
// stage(k+1) = 8 gld16, s_waitcnt vmcnt(8), raw s_barrier. XOR-swizzled
// both-sides. Bijective XCD remap; m = wgid>>1, n = wgid&1 (N=512 -> 2).
// EPI 0: relu -> fp8 store ; EPI 1: plain -> bf16 store ;
// EPI 2: relu with bias + dscale*cvec -> column-sum atomicAdd into sumOut
// ---------------------------------------------------------------------------
template<int K, int EPI>
__global__ __launch_bounds__(512, 2) void gemm_bt(
    const u16* __restrict__ A, const u16* __restrict__ B,
    const float* __restrict__ bias,
    u16* __restrict__ outB, u8* __restrict__ outF8,
    float* __restrict__ sumOut, const float* __restrict__ dscale,
    const float* __restrict__ cvec)
{
  __shared__ u16 As[2][256 * 64];
  __shared__ u16 Bs[2][256 * 64];
  const int nwg  = gridDim.x;
  const int q    = nwg >> 3, r = nwg & 7;
  const int xcd  = blockIdx.x & 7, loc = blockIdx.x >> 3;
  const int wgid = (xcd < r ? xcd * (q + 1) : r * (q + 1) + (xcd - r) * q) + loc;
  const int m0   = (wgid >> 1) * 256;
  const int n0   = (wgid & 1) * 256;

  const int tid  = threadIdx.x;
  const int w    = tid >> 6;
  const int lane = tid & 63;
  const int wm   = (w >> 2) * 128;   // wave row offset within tile
  const int wn   = (w & 3) * 64;     // wave col offset within tile
  const int l15  = lane & 15;
  const int lh   = lane >> 4;

  const f32x4 z4 = {0.f, 0.f, 0.f, 0.f};
  f32x4 acc[8][4];
#pragma unroll
  for (int m = 0; m < 8; ++m)
#pragma unroll
    for (int n = 0; n < 4; ++n) acc[m][n] = z4;

  // stage K-step kk into buffer kk&1 (A,B: 256 rows x 64 cols each,
  // 2048 chunks / 512 threads = 4 issues each -> 8 gld16 per thread)
  auto stage = [&](int kk) {
    const int b = kk & 1;
#pragma unroll
    for (int i = 0; i < 4; ++i) {
      const int cc  = i * 512 + w * 64 + lane;     // 16B chunk id, lane-contig
      const int row = cc >> 3;
      const int csw = (cc ^ row) & 7;              // swizzled source chunk
      const int ldsbase = (i * 512 + w * 64) * 8;  // u16 units, wave-uniform
      gld16(A + (size_t)(m0 + row) * K + kk * 64 + csw * 8, As[b] + ldsbase);
      gld16(B + (size_t)(n0 + row) * K + kk * 64 + csw * 8, Bs[b] + ldsbase);
    }
  };

  const int NK = K / 64;
  stage(0);

  for (int kk = 0; kk < NK; ++kk) {
    if (kk + 1 < NK) {
      stage(kk + 1);                                   // 8 more loads in flight
      asm volatile("s_waitcnt vmcnt(8)" ::: "memory"); // kk's 8 loads landed
    } else {
      asm volatile("s_waitcnt vmcnt(0)" ::: "memory");
    }
    __builtin_amdgcn_s_barrier();            // raw: does NOT drain vmcnt
    __builtin_amdgcn_sched_barrier(0);
    const u16* as = As[kk & 1];
    const u16* bs = Bs[kk & 1];
#pragma unroll
    for (int ks = 0; ks < 2; ++ks) {
      bf16x8 a[8], b[4];
#pragma unroll
      for (int m = 0; m < 8; ++m) {
        const int row = wm + m * 16 + l15;
        const int ch  = (ks * 4 + lh) ^ (row & 7);
        a[m] = *(const bf16x8*)&as[row * 64 + ch * 8];
      }
#pragma unroll
      for (int n = 0; n < 4; ++n) {
        const int row = wn + n * 16 + l15;
        const int ch  = (ks * 4 + lh) ^ (row & 7);
        b[n] = *(const bf16x8*)&bs[row * 64 + ch * 8];
      }
#pragma unroll
      for (int m = 0; m < 8; ++m)
#pragma unroll
        for (int n = 0; n < 4; ++n)
          acc[m][n] = __builtin_amdgcn_mfma_f32_16x16x32_bf16(a[m], b[n], acc[m][n], 0, 0, 0);
    }
    __builtin_amdgcn_sched_barrier(0);
    __builtin_amdgcn_s_barrier();            // all waves done reading buf[kk&1]
  }

  if (EPI == 2) {
#pragma unroll
    for (int n = 0; n < 4; ++n) {
      const int gc = n0 + wn + n * 16 + l15;
      const float bv = bias[gc];
      const float cv = cvec[gc];
      float p = 0.f;
#pragma unroll
      for (int m = 0; m < 8; ++m) {
        const float4 dm = *(const float4*)&dscale[m0 + wm + m * 16 + lh * 4];
        const float dd[4] = {dm.x, dm.y, dm.z, dm.w};
#pragma unroll
        for (int j = 0; j < 4; ++j) {
          float v = fmaxf(acc[m][n][j] + bv + dd[j] * cv, 0.f);
          p += (dd[j] > 0.f) ? v : 0.f;     // branchless pad guard (cndmask)
        }
      }
      p += __shfl_xor(p, 16);
      p += __shfl_xor(p, 32);
      if (lane < 16) atomicAdd(&sumOut[gc], p);
    }
  } else {
#pragma unroll
    for (int m = 0; m < 8; ++m) {
#pragma unroll
      for (int j = 0; j < 4; ++j) {
        const int gr = m0 + wm + m * 16 + lh * 4 + j;
#pragma unroll
        for (int n = 0; n < 4; ++n) {
          const int gc = n0 + wn + n * 16 + l15;
          const float v = acc[m][n][j] + bias[gc];
          if (EPI == 0) outF8[(size_t)gr * NH + gc] = f2fp8(fmaxf(v, 0.f));
          else          outB[(size_t)gr * NH + gc] = f2bf(v);
        }
      }
    }
  }
}

// ---------------------------------------------------------------------------
// Fused prologue prep:
//  region 0: W1a [128x512]  -> W1aT bf16 (transposed)   (256 blocks)
//  region 1: W1b [512x512]  -> W1bN bf16 (straight)     (1024 blocks)
//  region 2: W2a [512x512]  -> W2aT bf16 (transposed)   (1024 blocks)
//  region 3: x f32 -> bf16 padded                       (6272 blocks)
//  region 4: deg histogram over dst                     (2344 blocks)
//  region 5: cvec[j] += chunk of b1b@W2a                (32 blocks; memset'd)
// ---------------------------------------------------------------------------
#define PREP_R3 6272  // MPAD*32/256
struct PrepArgs {
  const float* W1a; u16* W1aT;
  const float* W1b; u16* W1bN;
  const float* W2a; u16* W2aT;
  const float4* x4; uint64_t* xb;
  const int* ei; int* deg;
  const float* b1b; float* cvec;
};

__device__ __forceinline__ void cvtWT_one(const float* W, u16* T,
                                          int Kd, int Nd, int t) {
  if (t >= Kd * Nd) return;
  int k = t / Nd, n = t - k * Nd;
  T[n * Kd + k] = f2bf(W[t]);
}

__global__ __launch_bounds__(256) void prep_all(PrepArgs p) {
  const int bid = blockIdx.x;
  if (bid < 256) {
    cvtWT_one(p.W1a, p.W1aT, ND, NH, bid * 256 + threadIdx.x);
  } else if (bid < 1280) {
    int t = (bid - 256) * 256 + threadIdx.x;          // straight cast, no transpose
    if (t < NH * NH) p.W1bN[t] = f2bf(p.W1b[t]);
  } else if (bid < 2304) {
    cvtWT_one(p.W2a, p.W2aT, NH, NH, (bid - 1280) * 256 + threadIdx.x);
  } else if (bid < 2304 + PREP_R3) {
    int t = (bid - 2304) * 256 + threadIdx.x;
    if (t >= MPAD * 32) return;
    int row = t >> 5;
    uint64_t qv = 0;
    if (row < NN) qv = f42bfq(p.x4[t]);
    p.xb[t] = qv;
  } else if (bid < 2304 + PREP_R3 + 2344) {
    int e = (bid - 2304 - PREP_R3) * 256 + threadIdx.x;
    if (e < NE) atomicAdd(&p.deg[p.ei[NE + e]], 1);
  } else {
    const int bb = bid - 2304 - PREP_R3 - 2344;       // 0..31
    const int kc = bb >> 1;
    const int j  = (bb & 1) * 256 + threadIdx.x;
    float acc = 0.f;
#pragma unroll
    for (int k = kc * 32; k < kc * 32 + 32; ++k)
      acc += p.b1b[k] * p.W2a[k * NH + j];
    atomicAdd(&p.cvec[j], acc);
  }
}

// ---------------- CSR construction ----------------
__global__ void deg_partial(const int* __restrict__ deg, int* __restrict__ bsum) {
  const int i = blockIdx.x * 256 + threadIdx.x;
  int v = (i < NN) ? deg[i] : 0;
#pragma unroll
  for (int o = 1; o < 64; o <<= 1) v += __shfl_xor(v, o);
  __shared__ int ws[4];
  if ((threadIdx.x & 63) == 0) ws[threadIdx.x >> 6] = v;
  __syncthreads();
  if (threadIdx.x == 0) bsum[blockIdx.x] = ws[0] + ws[1] + ws[2] + ws[3];
}

// scan_apply with inline bsum scan; emits rowptr, cursor, dscale (MPAD-wide)
__global__ void scan_apply(const int* __restrict__ deg, const int* __restrict__ bsum,
                           int* __restrict__ rowptr, int* __restrict__ cursor,
                           float* __restrict__ dscale) {
  __shared__ int s[256];
  const int t = threadIdx.x;
  int bv = (t < NB) ? bsum[t] : 0;
  s[t] = bv;
  __syncthreads();
  for (int o = 1; o < 256; o <<= 1) {
    int u = (t >= o) ? s[t - o] : 0;
    __syncthreads();
    s[t] += u;
    __syncthreads();
  }
  const int boff = (blockIdx.x == 0) ? 0 : s[blockIdx.x - 1];
  __syncthreads();
  const int i = blockIdx.x * 256 + t;
  int v = (i < NN) ? deg[i] : 0;
  s[t] = v;
  __syncthreads();
  for (int o = 1; o < 256; o <<= 1) {
    int u = (t >= o) ? s[t - o] : 0;
    __syncthreads();
    s[t] += u;
    __syncthreads();
  }
  if (i < NN) {
    int ex = boff + s[t] - v;
    rowptr[i] = ex;
    cursor[i] = ex;
    dscale[i] = 1.0f + (float)v;
  } else if (i < MPAD) {
    dscale[i] = 0.0f;
  }
  if (blockIdx.x == 0 && t == 0) rowptr[NN] = NE;
}

// covers dscale rows [NB*256, MPAD) (scan grid only reaches NB*256 = 50176)
// (NB*256 == MPAD so nothing extra needed; kept for safety if MPAD grows)

__global__ void fill_csr(const int* __restrict__ ei, int* __restrict__ cursor,
                         int* __restrict__ csr) {
  int e = blockIdx.x * 256 + threadIdx.x;
  if (e >= NE) return;
  int d = ei[NE + e];
  int p = atomicAdd(&cursor[d], 1);
  csr[p] = ei[e];
}

// ---------------- gather-reduce aggregations ----------------
// conv1: hb1[i][:] = bf16( xb[i][:] + sum_{e} xb[csr[e]][:] )  (xb bf16, dim 128)
__global__ __launch_bounds__(256) void gather_x(
    const u16* __restrict__ xb, const int* __restrict__ rowptr,
    const int* __restrict__ csr, u16* __restrict__ hb1) {
  const int wid  = blockIdx.x * 4 + (threadIdx.x >> 6);
  const int lane = threadIdx.x & 63;
  if (wid >= MPAD) return;
  float a0 = 0.f, a1 = 0.f;
  if (wid < NN) {
    uint32_t v = *(const uint32_t*)(xb + (size_t)wid * ND + lane * 2);
    a0 = bf2f((u16)v); a1 = bf2f((u16)(v >> 16));
    const int beg = rowptr[wid], end = rowptr[wid + 1];
    int e = beg;
    for (; e + 3 < end; e += 4) {
      int s0 = csr[e], s1 = csr[e + 1], s2 = csr[e + 2], s3 = csr[e + 3];
      uint32_t v0 = *(const uint32_t*)(xb + (size_t)s0 * ND + lane * 2);
      uint32_t v1 = *(const uint32_t*)(xb + (size_t)s1 * ND + lane * 2);
      uint32_t v2 = *(const uint32_t*)(xb + (size_t)s2 * ND + lane * 2);
      uint32_t v3 = *(const uint32_t*)(xb + (size_t)s3 * ND + lane * 2);
      a0 += bf2f((u16)v0) + bf2f((u16)v1) + bf2f((u16)v2) + bf2f((u16)v3);
      a1 += bf2f((u16)(v0 >> 16)) + bf2f((u16)(v1 >> 16)) +
            bf2f((u16)(v2 >> 16)) + bf2f((u16)(v3 >> 16));
    }
    for (; e < end; ++e) {
      int s0 = csr[e];
      uint32_t v0 = *(const uint32_t*)(xb + (size_t)s0 * ND + lane * 2);
      a0 += bf2f((u16)v0);
      a1 += bf2f((u16)(v0 >> 16));
    }
  }
  uint32_t o = (uint32_t)f2bf(a0) | ((uint32_t)f2bf(a1) << 16);
  *(uint32_t*)(hb1 + (size_t)wid * ND + lane * 2) = o;
}

// fp8 x8 decode -> packed f32x2 accumulate (v_pk_add_f32)
__device__ __forceinline__ void acc_fp8x8(f32x2* acc, uint2 v) {
  acc[0] += fp8x2_f32<false>(v.x);
  acc[1] += fp8x2_f32<true >(v.x);
  acc[2] += fp8x2_f32<false>(v.y);
  acc[3] += fp8x2_f32<true >(v.y);
}

// conv2 agg on r1: g[i][:] = bf16( R8[i][:] + sum_{e} R8[csr[e]][:] )  (fp8, dim 512)
__global__ __launch_bounds__(256) void gather_h(
    const u8* __restrict__ R8, const int* __restrict__ rowptr,
    const int* __restrict__ csr, u16* __restrict__ g) {
  const int wid  = blockIdx.x * 4 + (threadIdx.x >> 6);
  const int lane = threadIdx.x & 63;
  if (wid >= MPAD) return;
  f32x2 acc[4];
#pragma unroll
  for (int j = 0; j < 4; ++j) acc[j] = (f32x2){0.f, 0.f};
  if (wid < NN) {
    acc_fp8x8(acc, *(const uint2*)(R8 + (size_t)wid * NH + lane * 8));
    const int beg = rowptr[wid], end = rowptr[wid + 1];
    int e = beg;
    for (; e + 3 < end; e += 4) {
      int s0 = csr[e], s1 = csr[e + 1], s2 = csr[e + 2], s3 = csr[e + 3];
      uint2 v0 = *(const uint2*)(R8 + (size_t)s0 * NH + lane * 8);
      uint2 v1 = *(const uint2*)(R8 + (size_t)s1 * NH + lane * 8);
      uint2 v2 = *(const uint2*)(R8 + (size_t)s2 * NH + lane * 8);
      uint2 v3 = *(const uint2*)(R8 + (size_t)s3 * NH + lane * 8);
      acc_fp8x8(acc, v0);
      acc_fp8x8(acc, v1);
      acc_fp8x8(acc, v2);
      acc_fp8x8(acc, v3);
    }
    for (; e < end; ++e) {
      int s0 = csr[e];
      acc_fp8x8(acc, *(const uint2*)(R8 + (size_t)s0 * NH + lane * 8));
    }
  }
  union { u16 u[8]; uint4 q; } o;
#pragma unroll
  for (int j = 0; j < 4; ++j) {
    o.u[j * 2]     = f2bf(acc[j].x);
    o.u[j * 2 + 1] = f2bf(acc[j].y);
  }
  *(uint4*)(g + (size_t)wid * NH + lane * 8) = o.q;
}

// ---------------- parallel final epilogue ----------------
__global__ __launch_bounds__(256) void ff1(const float* __restrict__ s,
                                           const float* __restrict__ W2b,
                                           float* __restrict__ pooled,
                                           const float* __restrict__ bfv,
                                           float* __restrict__ out) {
  const int b = blockIdx.x;
  if (b == 32) {
    if (threadIdx.x < NO) out[threadIdx.x] = bfv[threadIdx.x];
    return;
  }
  const int kc = b >> 1;
  const int j  = (b & 1) * 256 + threadIdx.x;
  const float invN = 1.0f / (float)NN;
  float acc = 0.f;
#pragma unroll
  for (int k = kc * 32; k < kc * 32 + 32; ++k)
    acc += s[k] * W2b[k * NH + j];
  atomicAdd(&pooled[j], acc * invN);
}

__global__ __launch_bounds__(128) void ff2(const float* __restrict__ pooled,
                                           const float* __restrict__ b2b,
                                           const float* __restrict__ Wf,
                                           float* __restrict__ out) {
  const int kc = blockIdx.x;
  const int j  = threadIdx.x;
  float acc = 0.f;
#pragma unroll
  for (int k = kc * 32; k < kc * 32 + 32; ++k)
    acc += (pooled[k] + b2b[k]) * Wf[k * NO + j];
  atomicAdd(&out[j], acc);
}

__global__ void ws_sentinel(float* out) {
  if (threadIdx.x < NO) out[threadIdx.x] = -12345.0f;
}

extern "C" void kernel_launch(void* const* d_in, const int* in_sizes, int n_in,
                              void* d_out, int out_size, void* d_ws, size_t ws_size,
                              hipStream_t stream) {
  const float* x   = (const float*)d_in[0];
  const int*   ei  = (const int*)d_in[1];
  const float* W1a = (const float*)d_in[2];
  const float* b1a = (const float*)d_in[3];
  const float* W1b = (const float*)d_in[4];
  const float* b1b = (const float*)d_in[5];
  const float* W2a = (const float*)d_in[6];
  const float* b2a = (const float*)d_in[7];
  const float* W2b = (const float*)d_in[8];
  const float* b2b = (const float*)d_in[9];
  const float* Wf  = (const float*)d_in[10];
  const float* bfv = (const float*)d_in[11];
  float* out = (float*)d_out;

  const size_t XB  = (size_t)MPAD * ND * 2;  // bf16 x
  const size_t HB1 = (size_t)MPAD * ND * 2;  // bf16 agg1
  const size_t GB  = (size_t)MPAD * NH * 2;  // bf16 (g = agg2(r1))
  const size_t R8B = (size_t)MPAD * NH;      // fp8 (r1)
  const size_t WB  = (size_t)NH * ND * 2 + 3 * (size_t)NH * NH * 2;
  const size_t CSRB = (size_t)(NN + 1) * 4 + 2 * (size_t)NN * 4 + (size_t)NE * 4
                      + 2 * (size_t)NB * 4 + (size_t)MPAD * 4;
  const size_t NEED = XB + HB1 + GB + R8B + WB + CSRB + 4 * NH * 4 + 32 * 256;
  if (ws_size < NEED) {
    ws_sentinel<<<1, 128, 0, stream>>>(out);
    return;
  }

  char* ws = (char*)d_ws;
  size_t off = 0;
  auto take = [&](size_t bytes) {
    char* p = ws + off;
    off = (off + bytes + 255) & ~(size_t)255;
    return p;
  };
  u16* xb  = (u16*)take(XB);
  u16* hb1 = (u16*)take(HB1);
  u16* G   = (u16*)take(GB);
  u8*  R8  = (u8*)take(R8B);
  u16* W1aT = (u16*)take((size_t)NH * ND * 2);
  u16* W1bN = (u16*)take((size_t)NH * NH * 2);
  u16* W2aT = (u16*)take((size_t)NH * NH * 2);
  u16* WcT  = (u16*)take((size_t)NH * NH * 2);
  int* cursor = (int*)take((size_t)NN * 4);
  int* rowptr = (int*)take((size_t)(NN + 1) * 4);
  int* csr    = (int*)take((size_t)NE * 4);
  int* bsum   = (int*)take((size_t)NB * 4);
  float* dscale = (float*)take((size_t)MPAD * 4);
  // single contiguous zero region: deg (200KB) + svec/pooled/zero512/cvec (8KB)
  int*   deg     = (int*)take((size_t)NN * 4);
  float* svec    = (float*)take((size_t)NH * 4);
  float* pooled  = (float*)take((size_t)NH * 4);
  float* zero512 = (float*)take((size_t)NH * 4);
  float* cvec    = (float*)take((size_t)NH * 4);

  (void)hipMemsetAsync(deg, 0, (size_t)((char*)(cvec + NH) - (char*)deg), stream);

  // fused prologue (weights, x->bf16, deg histogram, cvec = b1b@W2a)
  PrepArgs pa;
  pa.W1a = W1a; pa.W1aT = W1aT;
  pa.W1b = W1b; pa.W1bN = W1bN;
  pa.W2a = W2a; pa.W2aT = W2aT;
  pa.x4 = (const float4*)x; pa.xb = (uint64_t*)xb;
  pa.ei = ei; pa.deg = deg;
  pa.b1b = b1b; pa.cvec = cvec;
  prep_all<<<2304 + PREP_R3 + 2344 + 32, 256, 0, stream>>>(pa);

  // WcT[n][k] = sum_j W2aT[n][j] * W1bN[k][j]  == (W1b@W2a)^T, bf16
  // M=512 -> 2 m-tiles x 2 n-tiles = 4 blocks
  gemm_bt<NH, 1><<<4, 512, 0, stream>>>(W2aT, W1bN, zero512, WcT, nullptr, nullptr, nullptr, nullptr);

  // CSR: block sums -> fused scan (bsum scanned in-block) -> csr fill
  deg_partial<<<NB, 256, 0, stream>>>(deg, bsum);
  scan_apply<<<NB, 256, 0, stream>>>(deg, bsum, rowptr, cursor, dscale);
  fill_csr<<<(NE + 255) / 256, 256, 0, stream>>>(ei, cursor, csr);

  // conv1 first layer only: r1 = relu(agg1@W1a + b1a) stored fp8
  gather_x<<<MPAD / 4, 256, 0, stream>>>(xb, rowptr, csr, hb1);
  gemm_bt<ND, 0><<<(MPAD / 256) * 2, 512, 0, stream>>>(hb1, W1aT, b1a, nullptr, R8, nullptr, nullptr, nullptr);

  // conv2 agg directly on r1 (W1b folded into Wc), then fused EPI2 GEMM:
  // svec[c] = sum_i relu( (g@Wc)[i][c] + b2a[c] + dscale_i*cvec[c] )
  gather_h<<<MPAD / 4, 256, 0, stream>>>(R8, rowptr, csr, G);
  gemm_bt<NH, 2><<<(MPAD / 256) * 2, 512, 0, stream>>>(G, WcT, b2a, nullptr, nullptr, svec, dscale, cvec);

  // parallel epilogue: pooled = (svec/NN)@W2b (+b2b in ff2), out = ... @Wf + bf
  ff1<<<33, 256, 0, stream>>>(svec, W2b, pooled, bfv, out);
  ff2<<<16, 128, 0, stream>>>(pooled, b2b, Wf, out);
}

// Round 19
// 239.655 us; speedup vs baseline: 1.0515x; 1.0515x over previous
//
#include <hip/hip_runtime.h>
#include <stdint.h>

#define NN 50000
#define NE 600000
#define ND 128
#define NH 512
#define NO 128
#define MPAD 50048  // 391 * 128
#define NB 196      // ceil(NN/256) scan blocks

typedef unsigned short u16;
typedef uint8_t u8;
typedef __attribute__((ext_vector_type(8))) short bf16x8;
typedef __attribute__((ext_vector_type(4))) float f32x4;
typedef __attribute__((ext_vector_type(2))) float f32x2;

__device__ __forceinline__ u16 f2bf(float f) {
  union { float f; uint32_t u; } v; v.f = f;
  uint32_t u = v.u;
  uint32_t r = (u + 0x7fffu + ((u >> 16) & 1u)) >> 16;
  return (u16)r;
}
__device__ __forceinline__ float bf2f(u16 h) {
  union { uint32_t u; float f; } v; v.u = ((uint32_t)h) << 16; return v.f;
}
__device__ __forceinline__ uint64_t f42bfq(float4 v) {
  union { u16 u[4]; uint64_t q; } o;
  o.u[0] = f2bf(v.x); o.u[1] = f2bf(v.y); o.u[2] = f2bf(v.z); o.u[3] = f2bf(v.w);
  return o.q;
}

// ---- fp8 e4m3 (OCP) encode/decode: HW cvt on gfx950, SW fallback ----
#if defined(__has_builtin)
#if __has_builtin(__builtin_amdgcn_cvt_pk_f32_fp8) && __has_builtin(__builtin_amdgcn_cvt_pk_fp8_f32)
#define HW_FP8 1
#endif
#endif
#ifndef HW_FP8
#define HW_FP8 0
#endif

__device__ __forceinline__ u8 f2fp8(float f) {
#if HW_FP8
  return (u8)(__builtin_amdgcn_cvt_pk_fp8_f32(f, f, 0, false) & 0xff);
#else
  union { float f; uint32_t u; } v; v.f = f;
  uint32_t s = v.u >> 31;
  float a = fabsf(f);
  if (a >= 448.f) return (u8)((s << 7) | 0x7e);
  if (a < 0.015625f) {
    uint32_t m = (uint32_t)(a * 512.0f + 0.5f);
    if (m > 7) return (u8)((s << 7) | 8);
    return (u8)((s << 7) | m);
  }
  uint32_t u = v.u & 0x7fffffff;
  uint32_t r = u + 0x7FFFF + ((u >> 20) & 1);
  int e8 = (int)(r >> 23) - 120;
  if (e8 >= 16) return (u8)((s << 7) | 0x7e);
  return (u8)((s << 7) | ((uint32_t)e8 << 3) | ((r >> 20) & 7));
#endif
}

template<bool HI>
__device__ __forceinline__ f32x2 fp8x2_f32(uint32_t w) {
#if HW_FP8
  return __builtin_amdgcn_cvt_pk_f32_fp8((int)w, HI);
#else
  uint32_t h = HI ? (w >> 16) : w;
  f32x2 r;
  for (int i = 0; i < 2; ++i) {
    uint32_t b = (h >> (i * 8)) & 0xff;
    uint32_t s = (b >> 7) & 1, e = (b >> 3) & 15, m = b & 7;
    float t;
    if (e == 0) t = (float)m * 0.001953125f;
    else { union { uint32_t u; float f; } v; v.u = ((e + 120) << 23) | (m << 20); t = v.f; }
    r[i] = s ? -t : t;
  }
  return r;
#endif
}

__device__ __forceinline__ void gld16(const u16* g, u16* l) {
  __builtin_amdgcn_global_load_lds(
      (const __attribute__((address_space(1))) void*)g,
      (__attribute__((address_space(3))) void*)l, 16, 0, 0);
}

// ---------------------------------------------------------------------------
// GEMM: C[M,512] = A[M,K](bf16) @ B^T   B stored transposed [512,K] bf16
// T4 counted-vmcnt pipeline (r13 verified): A,B double-buffered in LDS;
// stage(k+1), s_waitcnt vmcnt(8), raw s_barrier — prefetch survives barrier.
// XOR-swizzled both-sides; bijective XCD remap. (128² tile: r18's 256² A/B
// showed EPI2 invariant to tile size — this structure is the family optimum.)
// EPI 0: relu -> fp8 store (r1) ; EPI 1: plain -> bf16 store (WcT) ;
// EPI 2: relu with bias + dscale*cvec -> column-sum atomicAdd into sumOut
// ---------------------------------------------------------------------------
template<int K, int EPI>
__global__ __launch_bounds__(256) void gemm_bt(
    const u16* __restrict__ A, const u16* __restrict__ B,
    const float* __restrict__ bias,
    u16* __restrict__ outB, u8* __restrict__ outF8,
    float* __restrict__ sumOut, const float* __restrict__ dscale,
    const float* __restrict__ cvec)
{
  __shared__ u16 As[2][128 * 64];
  __shared__ u16 Bs[2][128 * 64];
  const int nwg  = gridDim.x;
  const int q    = nwg >> 3, r = nwg & 7;
  const int xcd  = blockIdx.x & 7, loc = blockIdx.x >> 3;
  const int wgid = (xcd < r ? xcd * (q + 1) : r * (q + 1) + (xcd - r) * q) + loc;
  const int m0   = (wgid >> 2) * 128;
  const int n0   = (wgid & 3) * 128;

  const int tid  = threadIdx.x;
  const int w    = tid >> 6;
  const int lane = tid & 63;
  const int wm   = (w >> 1) * 64;
  const int wn   = (w & 1) * 64;
  const int l15  = lane & 15;
  const int lh   = lane >> 4;

  // EPI2: hoist dscale loads before the K-loop (hidden under pipeline)
  float4 dsc[4];
  if (EPI == 2) {
#pragma unroll
    for (int m = 0; m < 4; ++m)
      dsc[m] = *(const float4*)&dscale[m0 + wm + m * 16 + lh * 4];
  }

  const f32x4 z4 = {0.f, 0.f, 0.f, 0.f};
  f32x4 acc[4][4];
#pragma unroll
  for (int m = 0; m < 4; ++m)
#pragma unroll
    for (int n = 0; n < 4; ++n) acc[m][n] = z4;

  // stage K-step kk into buffer kk&1 (8 gld16: pre-swizzled src, linear dest)
  auto stage = [&](int kk) {
    const int b = kk & 1;
#pragma unroll
    for (int i = 0; i < 4; ++i) {
      const int cc  = i * 256 + w * 64 + lane;     // 16B chunk id, lane-contig
      const int row = cc >> 3;
      const int csw = (cc ^ row) & 7;              // swizzled source chunk
      const int ldsbase = (i * 256 + w * 64) * 8;  // u16 units, wave-uniform
      gld16(A + (size_t)(m0 + row) * K + kk * 64 + csw * 8, As[b] + ldsbase);
      gld16(B + (size_t)(n0 + row) * K + kk * 64 + csw * 8, Bs[b] + ldsbase);
    }
  };

  const int NK = K / 64;
  stage(0);

  for (int kk = 0; kk < NK; ++kk) {
    if (kk + 1 < NK) {
      stage(kk + 1);                                   // 8 more loads in flight
      asm volatile("s_waitcnt vmcnt(8)" ::: "memory"); // kk's 8 loads landed
    } else {
      asm volatile("s_waitcnt vmcnt(0)" ::: "memory");
    }
    __builtin_amdgcn_s_barrier();            // raw: does NOT drain vmcnt
    __builtin_amdgcn_sched_barrier(0);
    const u16* as = As[kk & 1];
    const u16* bs = Bs[kk & 1];
#pragma unroll
    for (int ks = 0; ks < 2; ++ks) {
      bf16x8 a[4], b[4];
#pragma unroll
      for (int m = 0; m < 4; ++m) {
        const int row = wm + m * 16 + l15;
        const int ch  = (ks * 4 + lh) ^ (row & 7);
        a[m] = *(const bf16x8*)&as[row * 64 + ch * 8];
      }
#pragma unroll
      for (int n = 0; n < 4; ++n) {
        const int row = wn + n * 16 + l15;
        const int ch  = (ks * 4 + lh) ^ (row & 7);
        b[n] = *(const bf16x8*)&bs[row * 64 + ch * 8];
      }
#pragma unroll
      for (int m = 0; m < 4; ++m)
#pragma unroll
        for (int n = 0; n < 4; ++n)
          acc[m][n] = __builtin_amdgcn_mfma_f32_16x16x32_bf16(a[m], b[n], acc[m][n], 0, 0, 0);
    }
    __builtin_amdgcn_sched_barrier(0);
    __builtin_amdgcn_s_barrier();            // all waves done reading buf[kk&1]
  }

  if (EPI == 2) {
#pragma unroll
    for (int n = 0; n < 4; ++n) {
      const int gc = n0 + wn + n * 16 + l15;
      const float bv = bias[gc];
      const float cv = cvec[gc];
      float p = 0.f;
#pragma unroll
      for (int m = 0; m < 4; ++m) {
        const float dd[4] = {dsc[m].x, dsc[m].y, dsc[m].z, dsc[m].w};
#pragma unroll
        for (int j = 0; j < 4; ++j) {
          float v = fmaxf(acc[m][n][j] + bv + dd[j] * cv, 0.f);
          p += (dd[j] > 0.f) ? v : 0.f;     // branchless pad guard (cndmask)
        }
      }
      p += __shfl_xor(p, 16);
      p += __shfl_xor(p, 32);
      if (lane < 16) atomicAdd(&sumOut[gc], p);
    }
  } else {
#pragma unroll
    for (int m = 0; m < 4; ++m) {
#pragma unroll
      for (int j = 0; j < 4; ++j) {
        const int gr = m0 + wm + m * 16 + lh * 4 + j;
#pragma unroll
        for (int n = 0; n < 4; ++n) {
          const int gc = n0 + wn + n * 16 + l15;
          const float v = acc[m][n][j] + bias[gc];
          if (EPI == 0) outF8[(size_t)gr * NH + gc] = f2fp8(fmaxf(v, 0.f));
          else          outB[(size_t)gr * NH + gc] = f2bf(v);
        }
      }
    }
  }
}

// ---------------------------------------------------------------------------
// Fused prologue prep:
//  region 0: W1a [128x512]  -> W1aT bf16 (transposed)   (256 blocks)
//  region 1: W1b [512x512]  -> W1bN bf16 (straight)     (1024 blocks)
//  region 2: W2a [512x512]  -> W2aT bf16 (transposed)   (1024 blocks)
//  region 3: x f32 -> bf16 padded                       (6256 blocks)
//  region 4: deg histogram over dst                     (2344 blocks)
//  region 5: cvec[j] += chunk of b1b@W2a                (32 blocks; memset'd)
// ---------------------------------------------------------------------------
struct PrepArgs {
  const float* W1a; u16* W1aT;
  const float* W1b; u16* W1bN;
  const float* W2a; u16* W2aT;
  const float4* x4; uint64_t* xb;
  const int* ei; int* deg;
  const float* b1b; float* cvec;
};

__device__ __forceinline__ void cvtWT_one(const float* W, u16* T,
                                          int Kd, int Nd, int t) {
  if (t >= Kd * Nd) return;
  int k = t / Nd, n = t - k * Nd;
  T[n * Kd + k] = f2bf(W[t]);
}

__global__ __launch_bounds__(256) void prep_all(PrepArgs p) {
  const int bid = blockIdx.x;
  if (bid < 256) {
    cvtWT_one(p.W1a, p.W1aT, ND, NH, bid * 256 + threadIdx.x);
  } else if (bid < 1280) {
    int t = (bid - 256) * 256 + threadIdx.x;          // straight cast, no transpose
    if (t < NH * NH) p.W1bN[t] = f2bf(p.W1b[t]);
  } else if (bid < 2304) {
    cvtWT_one(p.W2a, p.W2aT, NH, NH, (bid - 1280) * 256 + threadIdx.x);
  } else if (bid < 2304 + 6256) {
    int t = (bid - 2304) * 256 + threadIdx.x;
    if (t >= MPAD * 32) return;
    int row = t >> 5;
    uint64_t qv = 0;
    if (row < NN) qv = f42bfq(p.x4[t]);
    p.xb[t] = qv;
  } else if (bid < 2304 + 6256 + 2344) {
    int e = (bid - 2304 - 6256) * 256 + threadIdx.x;
    if (e < NE) atomicAdd(&p.deg[p.ei[NE + e]], 1);
  } else {
    const int bb = bid - 2304 - 6256 - 2344;          // 0..31
    const int kc = bb >> 1;
    const int j  = (bb & 1) * 256 + threadIdx.x;
    float acc = 0.f;
#pragma unroll
    for (int k = kc * 32; k < kc * 32 + 32; ++k)
      acc += p.b1b[k] * p.W2a[k * NH + j];
    atomicAdd(&p.cvec[j], acc);
  }
}

// ---------------- CSR construction ----------------
__global__ void deg_partial(const int* __restrict__ deg, int* __restrict__ bsum) {
  const int i = blockIdx.x * 256 + threadIdx.x;
  int v = (i < NN) ? deg[i] : 0;
#pragma unroll
  for (int o = 1; o < 64; o <<= 1) v += __shfl_xor(v, o);
  __shared__ int ws[4];
  if ((threadIdx.x & 63) == 0) ws[threadIdx.x >> 6] = v;
  __syncthreads();
  if (threadIdx.x == 0) bsum[blockIdx.x] = ws[0] + ws[1] + ws[2] + ws[3];
}

// scan_apply with inline bsum scan (scan_bsum launch eliminated):
// each block redundantly scans bsum[NB] in LDS for its own exclusive offset,
// then scans its deg chunk; emits rowptr, cursor, dscale; b0 sets rowptr[NN].
__global__ void scan_apply(const int* __restrict__ deg, const int* __restrict__ bsum,
                           int* __restrict__ rowptr, int* __restrict__ cursor,
                           float* __restrict__ dscale) {
  __shared__ int s[256];
  const int t = threadIdx.x;
  // phase 1: inclusive scan of bsum -> block offset
  int bv = (t < NB) ? bsum[t] : 0;
  s[t] = bv;
  __syncthreads();
  for (int o = 1; o < 256; o <<= 1) {
    int u = (t >= o) ? s[t - o] : 0;
    __syncthreads();
    s[t] += u;
    __syncthreads();
  }
  const int boff = (blockIdx.x == 0) ? 0 : s[blockIdx.x - 1];
  __syncthreads();
  // phase 2: scan own deg chunk
  const int i = blockIdx.x * 256 + t;
  int v = (i < NN) ? deg[i] : 0;
  s[t] = v;
  __syncthreads();
  for (int o = 1; o < 256; o <<= 1) {
    int u = (t >= o) ? s[t - o] : 0;
    __syncthreads();
    s[t] += u;
    __syncthreads();
  }
  if (i < NN) {
    int ex = boff + s[t] - v;
    rowptr[i] = ex;
    cursor[i] = ex;
    dscale[i] = 1.0f + (float)v;
  } else if (i < MPAD) {
    dscale[i] = 0.0f;
  }
  if (blockIdx.x == 0 && t == 0) rowptr[NN] = NE;
}

__global__ void fill_csr(const int* __restrict__ ei, int* __restrict__ cursor,
                         int* __restrict__ csr) {
  int e = blockIdx.x * 256 + threadIdx.x;
  if (e >= NE) return;
  int d = ei[NE + e];
  int p = atomicAdd(&cursor[d], 1);
  csr[p] = ei[e];
}

// ---------------- gather-reduce aggregations ----------------
// conv1: hb1[i][:] = bf16( xb[i][:] + sum_{e} xb[csr[e]][:] )  (xb bf16, dim 128)
__global__ __launch_bounds__(256) void gather_x(
    const u16* __restrict__ xb, const int* __restrict__ rowptr,
    const int* __restrict__ csr, u16* __restrict__ hb1) {
  const int wid  = blockIdx.x * 4 + (threadIdx.x >> 6);
  const int lane = threadIdx.x & 63;
  if (wid >= MPAD) return;
  float a0 = 0.f, a1 = 0.f;
  if (wid < NN) {
    uint32_t v = *(const uint32_t*)(xb + (size_t)wid * ND + lane * 2);
    a0 = bf2f((u16)v); a1 = bf2f((u16)(v >> 16));
    const int beg = rowptr[wid], end = rowptr[wid + 1];
    int e = beg;
    for (; e + 3 < end; e += 4) {
      int s0 = csr[e], s1 = csr[e + 1], s2 = csr[e + 2], s3 = csr[e + 3];
      uint32_t v0 = *(const uint32_t*)(xb + (size_t)s0 * ND + lane * 2);
      uint32_t v1 = *(const uint32_t*)(xb + (size_t)s1 * ND + lane * 2);
      uint32_t v2 = *(const uint32_t*)(xb + (size_t)s2 * ND + lane * 2);
      uint32_t v3 = *(const uint32_t*)(xb + (size_t)s3 * ND + lane * 2);
      a0 += bf2f((u16)v0) + bf2f((u16)v1) + bf2f((u16)v2) + bf2f((u16)v3);
      a1 += bf2f((u16)(v0 >> 16)) + bf2f((u16)(v1 >> 16)) +
            bf2f((u16)(v2 >> 16)) + bf2f((u16)(v3 >> 16));
    }
    for (; e < end; ++e) {
      int s0 = csr[e];
      uint32_t v0 = *(const uint32_t*)(xb + (size_t)s0 * ND + lane * 2);
      a0 += bf2f((u16)v0);
      a1 += bf2f((u16)(v0 >> 16));
    }
  }
  uint32_t o = (uint32_t)f2bf(a0) | ((uint32_t)f2bf(a1) << 16);
  *(uint32_t*)(hb1 + (size_t)wid * ND + lane * 2) = o;
}

// fp8 x8 decode -> packed f32x2 accumulate (v_pk_add_f32)
__device__ __forceinline__ void acc_fp8x8(f32x2* acc, uint2 v) {
  acc[0] += fp8x2_f32<false>(v.x);
  acc[1] += fp8x2_f32<true >(v.x);
  acc[2] += fp8x2_f32<false>(v.y);
  acc[3] += fp8x2_f32<true >(v.y);
}

// conv2 agg on r1: g[i][:] = bf16( R8[i][:] + sum_{e} R8[csr[e]][:] )  (fp8, dim 512)
__global__ __launch_bounds__(256) void gather_h(
    const u8* __restrict__ R8, const int* __restrict__ rowptr,
    const int* __restrict__ csr, u16* __restrict__ g) {
  const int wid  = blockIdx.x * 4 + (threadIdx.x >> 6);
  const int lane = threadIdx.x & 63;
  if (wid >= MPAD) return;
  f32x2 acc[4];
#pragma unroll
  for (int j = 0; j < 4; ++j) acc[j] = (f32x2){0.f, 0.f};
  if (wid < NN) {
    acc_fp8x8(acc, *(const uint2*)(R8 + (size_t)wid * NH + lane * 8));
    const int beg = rowptr[wid], end = rowptr[wid + 1];
    int e = beg;
    for (; e + 3 < end; e += 4) {
      int s0 = csr[e], s1 = csr[e + 1], s2 = csr[e + 2], s3 = csr[e + 3];
      uint2 v0 = *(const uint2*)(R8 + (size_t)s0 * NH + lane * 8);
      uint2 v1 = *(const uint2*)(R8 + (size_t)s1 * NH + lane * 8);
      uint2 v2 = *(const uint2*)(R8 + (size_t)s2 * NH + lane * 8);
      uint2 v3 = *(const uint2*)(R8 + (size_t)s3 * NH + lane * 8);
      acc_fp8x8(acc, v0);
      acc_fp8x8(acc, v1);
      acc_fp8x8(acc, v2);
      acc_fp8x8(acc, v3);
    }
    for (; e < end; ++e) {
      int s0 = csr[e];
      acc_fp8x8(acc, *(const uint2*)(R8 + (size_t)s0 * NH + lane * 8));
    }
  }
  union { u16 u[8]; uint4 q; } o;
#pragma unroll
  for (int j = 0; j < 4; ++j) {
    o.u[j * 2]     = f2bf(acc[j].x);
    o.u[j * 2 + 1] = f2bf(acc[j].y);
  }
  *(uint4*)(g + (size_t)wid * NH + lane * 8) = o.q;
}

// ---------------- parallel final epilogue ----------------
__global__ __launch_bounds__(256) void ff1(const float* __restrict__ s,
                                           const float* __restrict__ W2b,
                                           float* __restrict__ pooled,
                                           const float* __restrict__ bfv,
                                           float* __restrict__ out) {
  const int b = blockIdx.x;
  if (b == 32) {
    if (threadIdx.x < NO) out[threadIdx.x] = bfv[threadIdx.x];
    return;
  }
  const int kc = b >> 1;
  const int j  = (b & 1) * 256 + threadIdx.x;
  const float invN = 1.0f / (float)NN;
  float acc = 0.f;
#pragma unroll
  for (int k = kc * 32; k < kc * 32 + 32; ++k)
    acc += s[k] * W2b[k * NH + j];
  atomicAdd(&pooled[j], acc * invN);
}

__global__ __launch_bounds__(128) void ff2(const float* __restrict__ pooled,
                                           const float* __restrict__ b2b,
                                           const float* __restrict__ Wf,
                                           float* __restrict__ out) {
  const int kc = blockIdx.x;
  const int j  = threadIdx.x;
  float acc = 0.f;
#pragma unroll
  for (int k = kc * 32; k < kc * 32 + 32; ++k)
    acc += (pooled[k] + b2b[k]) * Wf[k * NO + j];
  atomicAdd(&out[j], acc);
}

__global__ void ws_sentinel(float* out) {
  if (threadIdx.x < NO) out[threadIdx.x] = -12345.0f;
}

extern "C" void kernel_launch(void* const* d_in, const int* in_sizes, int n_in,
                              void* d_out, int out_size, void* d_ws, size_t ws_size,
                              hipStream_t stream) {
  const float* x   = (const float*)d_in[0];
  const int*   ei  = (const int*)d_in[1];
  const float* W1a = (const float*)d_in[2];
  const float* b1a = (const float*)d_in[3];
  const float* W1b = (const float*)d_in[4];
  const float* b1b = (const float*)d_in[5];
  const float* W2a = (const float*)d_in[6];
  const float* b2a = (const float*)d_in[7];
  const float* W2b = (const float*)d_in[8];
  const float* b2b = (const float*)d_in[9];
  const float* Wf  = (const float*)d_in[10];
  const float* bfv = (const float*)d_in[11];
  float* out = (float*)d_out;

  const size_t XB  = (size_t)MPAD * ND * 2;  // 12.8 MB bf16 x
  const size_t HB1 = (size_t)MPAD * ND * 2;  // 12.8 MB bf16 agg1
  const size_t GB  = (size_t)MPAD * NH * 2;  // 51.25 MB bf16 (g = agg2(r1))
  const size_t R8B = (size_t)MPAD * NH;      // 25.6 MB fp8 (r1)
  const size_t WB  = (size_t)NH * ND * 2 + 3 * (size_t)NH * NH * 2;
  const size_t CSRB = (size_t)(NN + 1) * 4 + 2 * (size_t)NN * 4 + (size_t)NE * 4
                      + 2 * (size_t)NB * 4 + (size_t)MPAD * 4;
  const size_t NEED = XB + HB1 + GB + R8B + WB + CSRB + 4 * NH * 4 + 32 * 256;
  if (ws_size < NEED) {
    ws_sentinel<<<1, 128, 0, stream>>>(out);
    return;
  }

  char* ws = (char*)d_ws;
  size_t off = 0;
  auto take = [&](size_t bytes) {
    char* p = ws + off;
    off = (off + bytes + 255) & ~(size_t)255;
    return p;
  };
  u16* xb  = (u16*)take(XB);
  u16* hb1 = (u16*)take(HB1);
  u16* G   = (u16*)take(GB);
  u8*  R8  = (u8*)take(R8B);
  u16* W1aT = (u16*)take((size_t)NH * ND * 2);
  u16* W1bN = (u16*)take((size_t)NH * NH * 2);
  u16* W2aT = (u16*)take((size_t)NH * NH * 2);
  u16* WcT  = (u16*)take((size_t)NH * NH * 2);
  int* cursor = (int*)take((size_t)NN * 4);
  int* rowptr = (int*)take((size_t)(NN + 1) * 4);
  int* csr    = (int*)take((size_t)NE * 4);
  int* bsum   = (int*)take((size_t)NB * 4);
  float* dscale = (float*)take((size_t)MPAD * 4);
  // single contiguous zero region: deg (200KB) + svec/pooled/zero512/cvec (8KB)
  int*   deg     = (int*)take((size_t)NN * 4);
  float* svec    = (float*)take((size_t)NH * 4);
  float* pooled  = (float*)take((size_t)NH * 4);
  float* zero512 = (float*)take((size_t)NH * 4);
  float* cvec    = (float*)take((size_t)NH * 4);

  // one memset covers deg + svec + pooled + zero512 + cvec (contiguous takes;
  // 256B alignment padding between them is also zeroed — harmless)
  (void)hipMemsetAsync(deg, 0, (size_t)((char*)(cvec + NH) - (char*)deg), stream);

  // fused prologue (weights, x->bf16, deg histogram, cvec = b1b@W2a)
  PrepArgs pa;
  pa.W1a = W1a; pa.W1aT = W1aT;
  pa.W1b = W1b; pa.W1bN = W1bN;
  pa.W2a = W2a; pa.W2aT = W2aT;
  pa.x4 = (const float4*)x; pa.xb = (uint64_t*)xb;
  pa.ei = ei; pa.deg = deg;
  pa.b1b = b1b; pa.cvec = cvec;
  prep_all<<<2304 + 6256 + 2344 + 32, 256, 0, stream>>>(pa);

  // WcT[n][k] = sum_j W2aT[n][j] * W1bN[k][j]  == (W1b@W2a)^T, bf16
  gemm_bt<NH, 1><<<(512 / 128) * 4, 256, 0, stream>>>(W2aT, W1bN, zero512, WcT, nullptr, nullptr, nullptr, nullptr);

  // CSR: block sums -> fused scan (bsum scanned in-block) -> csr fill
  deg_partial<<<NB, 256, 0, stream>>>(deg, bsum);
  scan_apply<<<NB, 256, 0, stream>>>(deg, bsum, rowptr, cursor, dscale);
  fill_csr<<<(NE + 255) / 256, 256, 0, stream>>>(ei, cursor, csr);

  // conv1 first layer only: r1 = relu(agg1@W1a + b1a) stored fp8
  gather_x<<<(MPAD + 3) / 4, 256, 0, stream>>>(xb, rowptr, csr, hb1);
  gemm_bt<ND, 0><<<(MPAD / 128) * 4, 256, 0, stream>>>(hb1, W1aT, b1a, nullptr, R8, nullptr, nullptr, nullptr);

  // conv2 agg directly on r1 (W1b folded into Wc), then fused EPI2 GEMM:
  // svec[c] = sum_i relu( (g@Wc)[i][c] + b2a[c] + dscale_i*cvec[c] )
  gather_h<<<(MPAD + 3) / 4, 256, 0, stream>>>(R8, rowptr, csr, G);
  gemm_bt<NH, 2><<<(MPAD / 128) * 4, 256, 0, stream>>>(G, WcT, b2a, nullptr, nullptr, svec, dscale, cvec);

  // parallel epilogue: pooled = (svec/NN)@W2b (+b2b in ff2), out = ... @Wf + bf
  ff1<<<33, 256, 0, stream>>>(svec, W2b, pooled, bfv, out);
  ff2<<<16, 128, 0, stream>>>(pooled, b2b, Wf, out);
}